// Round 10
// baseline (1028.956 us; speedup 1.0000x reference)
//
#include <hip/hip_runtime.h>
#include <hip/hip_fp16.h>

#define H 64
#define MAXW 256        // max windows (scan width)
#define WSH 10          // 1024 nodes per window -> W = ceil(200000/1024) = 196 <= MAXW
#define WNODES (1 << WSH)
#define BINCH 4096      // edges per k_bin block
#define BPT (BINCH / 256)

typedef _Float16 half4_t __attribute__((ext_vector_type(4)));
typedef float floatx4 __attribute__((ext_vector_type(4)));

// ---------- window counting (LDS-aggregated; ~200 global atomics/block) ----------
__global__ __launch_bounds__(256) void k_wincount(const int* __restrict__ ei, int E,
                                                  int* __restrict__ winS, int* __restrict__ winD) {
    __shared__ int hs[MAXW], hd[MAXW];
    hs[threadIdx.x] = 0; hd[threadIdx.x] = 0;
    __syncthreads();
    int stride = gridDim.x * 256;
    for (int e = blockIdx.x * 256 + threadIdx.x; e < E; e += stride) {
        atomicAdd(&hs[ei[e] >> WSH], 1);
        atomicAdd(&hd[ei[E + e] >> WSH], 1);
    }
    __syncthreads();
    if (hs[threadIdx.x]) atomicAdd(&winS[threadIdx.x], hs[threadIdx.x]);
    if (hd[threadIdx.x]) atomicAdd(&winD[threadIdx.x], hd[threadIdx.x]);
}

// Single block: exclusive scan of both window-count arrays (MAXW wide, zero-padded).
__global__ void k_scan_win(const int* __restrict__ winS, const int* __restrict__ winD,
                           int* __restrict__ baseS, int* __restrict__ baseD,
                           int* __restrict__ curS, int* __restrict__ curD) {
    __shared__ int s[256];
    int tid = threadIdx.x;
    int v = winS[tid];
    s[tid] = v; __syncthreads();
    for (int off = 1; off < 256; off <<= 1) {
        int t = (tid >= off) ? s[tid - off] : 0; __syncthreads();
        s[tid] += t; __syncthreads();
    }
    int ex = s[tid] - v;
    baseS[tid] = ex; curS[tid] = ex;
    if (tid == 255) baseS[256] = s[255];
    __syncthreads();
    v = winD[tid];
    s[tid] = v; __syncthreads();
    for (int off = 1; off < 256; off <<= 1) {
        int t = (tid >= off) ? s[tid - off] : 0; __syncthreads();
        s[tid] += t; __syncthreads();
    }
    ex = s[tid] - v;
    baseD[tid] = ex; curD[tid] = ex;
    if (tid == 255) baseD[256] = s[255];
}

// ---------- bin: LDS counting-sort of a 4096-edge chunk by window ----------
// R10: ei read ONCE (dir1 swaps the same registers); wid[] dropped (flush
// recomputes w from rec.x>>WSH; LDS 41->37KB = 4 blocks/CU); per-node degree
// accumulated here via global atomics (deg is 1.6MB, L2-resident) so the
// downstream scatter kernel needs only ONE buf read.
__global__ __launch_bounds__(256) void k_bin(const int* __restrict__ ei, int E,
                                             int* __restrict__ gcurS, int* __restrict__ gcurD,
                                             int* __restrict__ degS, int* __restrict__ degD,
                                             int2* __restrict__ bufS, int2* __restrict__ bufD) {
    __shared__ int hist[MAXW];
    __shared__ int lbase[MAXW];
    __shared__ int lcur[MAXW];
    __shared__ int gdelta[MAXW];
    __shared__ int2 rec[BINCH];
    __shared__ int sscan[256];

    int tid = threadIdx.x;
    int e0 = blockIdx.x * BINCH;
    int n = min(BINCH, E - e0);

    int aa[BPT], bb[BPT];
#pragma unroll
    for (int j = 0; j < BPT; ++j) {
        int idx = tid + j * 256;
        if (idx < n) {
            aa[j] = ei[e0 + idx];
            bb[j] = ei[E + e0 + idx];
        }
    }

    for (int dir = 0; dir < 2; ++dir) {
        int* gcur = dir ? gcurD : gcurS;
        int* deg  = dir ? degD : degS;
        int2* buf = dir ? bufD : bufS;
        hist[tid] = 0;
        __syncthreads();
#pragma unroll
        for (int j = 0; j < BPT; ++j) {
            int idx = tid + j * 256;
            if (idx < n) {
                int k = dir ? bb[j] : aa[j];
                atomicAdd(&hist[k >> WSH], 1);
                atomicAdd(&deg[k], 1);          // global, L2-resident
            }
        }
        __syncthreads();
        {   // exclusive scan of hist
            int hv = hist[tid];
            sscan[tid] = hv; __syncthreads();
            for (int off = 1; off < 256; off <<= 1) {
                int t = (tid >= off) ? sscan[tid - off] : 0; __syncthreads();
                sscan[tid] += t; __syncthreads();
            }
            lbase[tid] = sscan[tid] - hv;
            lcur[tid] = lbase[tid];
        }
        __syncthreads();
#pragma unroll
        for (int j = 0; j < BPT; ++j) {
            int idx = tid + j * 256;
            if (idx < n) {
                int k = dir ? bb[j] : aa[j];
                int v = dir ? aa[j] : bb[j];
                int w = k >> WSH;
                int p = atomicAdd(&lcur[w], 1);
                rec[p] = make_int2(k, v);
            }
        }
        __syncthreads();
        {   // reserve one contiguous global chunk per non-empty window
            int c = hist[tid];
            int g = c ? atomicAdd(&gcur[tid], c) : 0;
            gdelta[tid] = g - lbase[tid];
        }
        __syncthreads();
        for (int j = tid; j < n; j += 256) {   // coalesced flush (runs sorted by window)
            int2 r = rec[j];
            int w = r.x >> WSH;
            *(long long*)&buf[gdelta[w] + j] = *(long long*)&r;
        }
        __syncthreads();
    }
}

// ---------- per-window scatter: deg -> LDS scan -> rp + cursors -> ONE buf read ----------
// Replaces k_build_win: the histogram pass (64MB buf re-read + 16M LDS atomics)
// is gone; deg comes precomputed from k_bin.
__global__ __launch_bounds__(256) void k_scat(const int2* __restrict__ bufS,
                                              const int2* __restrict__ bufD,
                                              const int* __restrict__ baseS,
                                              const int* __restrict__ baseD,
                                              const int* __restrict__ degS,
                                              const int* __restrict__ degD,
                                              int* __restrict__ rpS, int* __restrict__ rpD,
                                              int* __restrict__ colS, int* __restrict__ colD,
                                              int Ns, int Nd, int W) {
    __shared__ int cur[WNODES];
    __shared__ int sscan[256];
    int b = blockIdx.x, tid = threadIdx.x;
    int dir = (b >= W) ? 1 : 0;
    int w = dir ? b - W : b;
    const int2* buf = dir ? bufD : bufS;
    const int* base = dir ? baseD : baseS;
    const int* deg = dir ? degD : degS;
    int* rp = dir ? rpD : rpS;
    int* col = dir ? colD : colS;
    int N = dir ? Nd : Ns;
    int lo = w << WSH;
    int hi = min(lo + WNODES, N);
    int beg = base[w], end = base[w + 1];

    int i0 = tid * 4, gi = lo + i0;
    int v0 = (gi < hi) ? deg[gi] : 0;
    int v1 = (gi + 1 < hi) ? deg[gi + 1] : 0;
    int v2 = (gi + 2 < hi) ? deg[gi + 2] : 0;
    int v3 = (gi + 3 < hi) ? deg[gi + 3] : 0;
    int t = v0 + v1 + v2 + v3;
    sscan[tid] = t; __syncthreads();
    for (int off = 1; off < 256; off <<= 1) {
        int x = (tid >= off) ? sscan[tid - off] : 0; __syncthreads();
        sscan[tid] += x; __syncthreads();
    }
    int e0 = beg + sscan[tid] - t;
    int e1 = e0 + v0, e2 = e1 + v1, e3 = e2 + v2;
    cur[i0] = e0; cur[i0 + 1] = e1; cur[i0 + 2] = e2; cur[i0 + 3] = e3;
    if (gi < hi) rp[gi] = e0;
    if (gi + 1 < hi) rp[gi + 1] = e1;
    if (gi + 2 < hi) rp[gi + 2] = e2;
    if (gi + 3 < hi) rp[gi + 3] = e3;
    if (tid == 255 && hi == N) rp[N] = beg + sscan[255];
    __syncthreads();

    for (int r = beg + tid; r < end; r += 256) {
        int2 rc = buf[r];
        int p = atomicAdd(&cur[rc.x - lo], 1);
        col[p] = rc.y;
    }
}

// ---------- weight prep: fp32 [layer][rel][64][64] -> fp16 MFMA-fragment order ----------
__global__ __launch_bounds__(256) void k_prep_w(const float* __restrict__ Wl,
                                                const float* __restrict__ Wr,
                                                _Float16* __restrict__ w16) {
    int gid = blockIdx.x * 256 + threadIdx.x;     // 8 * 4096 = 32768
    int m = gid >> 12;
    int o = gid & 4095;
    int ks = o >> 10, g4 = (o >> 8) & 3, col = (o >> 2) & 63, j = o & 3;
    int k = (ks << 4) + (g4 << 2) + j;
    int lr = m & 1, rel = (m >> 1) & 1, layer = m >> 2;
    const float* Wsrc = lr ? Wr : Wl;
    w16[gid] = (_Float16)Wsrc[((layer * 2 + rel) * 64 + k) * 64 + col];
}

// ---------- feature init: fp16-only features ----------
__global__ __launch_bounds__(256) void k_init_x(const int* __restrict__ uid, const int* __restrict__ rid,
                         const float* __restrict__ recipe_x,
                         const float* __restrict__ user_emb, const float* __restrict__ recipe_emb,
                         const float* __restrict__ lin_w, const float* __restrict__ lin_b,
                         __half* __restrict__ xh_user, __half* __restrict__ xh_recipe,
                         int Nu, int Nr) {
    int n = blockIdx.x * 4 + (threadIdx.x >> 6);
    int h = threadIdx.x & 63;
    if (n < Nr) {
        float o = lin_b[h];
#pragma unroll
        for (int k = 0; k < 10; ++k)   // recipe_x addr wave-uniform -> broadcast load
            o = fmaf(recipe_x[(size_t)n * 10 + k], lin_w[k * H + h], o);
        o += recipe_emb[(size_t)rid[n] * H + h];
        xh_recipe[(size_t)n * H + h] = __float2half(o);
    }
    if (n < Nu) {
        xh_user[(size_t)n * H + h] = __float2half(user_emb[(size_t)uid[n] * H + h]);
    }
}

// ---------- SAGE layer: fp16 gather + MFMA epilogue (unchanged from R9) ----------
template <bool RELU>
__global__ __launch_bounds__(256, 6) void k_sage3(
    const __half* __restrict__ gsA, const __half* __restrict__ rtA,
    const int* __restrict__ rpA, const int* __restrict__ colA,
    const _Float16* __restrict__ wlA, const _Float16* __restrict__ wrA,
    const float* __restrict__ blA, __half* __restrict__ outA, int ndA, int nbA,
    const __half* __restrict__ gsB, const __half* __restrict__ rtB,
    const int* __restrict__ rpB, const int* __restrict__ colB,
    const _Float16* __restrict__ wlB, const _Float16* __restrict__ wrB,
    const float* __restrict__ blB, __half* __restrict__ outB, int ndB) {
    const __half* gs; const __half* rt; const int* rp; const int* col;
    const _Float16* wl16; const _Float16* wr16; const float* bl; __half* outh;
    int n_dst, bid;
    if (blockIdx.x < (unsigned)nbA) {
        gs = gsA; rt = rtA; rp = rpA; col = colA;
        wl16 = wlA; wr16 = wrA; bl = blA; outh = outA; n_dst = ndA; bid = blockIdx.x;
    } else {
        gs = gsB; rt = rtB; rp = rpB; col = colB;
        wl16 = wlB; wr16 = wrB; bl = blB; outh = outB; n_dst = ndB; bid = blockIdx.x - nbA;
    }

    int wave = threadIdx.x >> 6, lane = threadIdx.x & 63;
    int c = lane & 15, g = lane >> 4;          // group g owns node local=wave*4+g
    __shared__ __align__(16) _Float16 smh[16][72];   // [node][feat] mean, stride 72
    __shared__ __align__(16) _Float16 sxh[16][72];   // [node][feat] root

    int local = (wave << 2) + g;
    int n = bid * 16 + local;
    if (n < n_dst) {
        const uint2* xs = (const uint2*)gs;    // fp16 row = 128B = 16 x uint2
        uint2 xdu = ((const uint2*)rt)[(n << 4) + c];   // root row, overlaps gather
        int beg = rp[n], end = rp[n + 1];
        __half2 z = __float2half2_rn(0.f);
        __half2 l0 = z, l1 = z, l2 = z, l3 = z;   // lo pair (features 4c, 4c+1)
        __half2 h0 = z, h1 = z, h2 = z, h3 = z;   // hi pair (features 4c+2, 4c+3)
        int e = beg;
        for (; e + 7 < end; e += 8) {           // 8 loads in flight per group
            int r0 = col[e];
            int r1 = col[e + 1];
            int r2 = col[e + 2];
            int r3 = col[e + 3];
            int r4 = col[e + 4];
            int r5 = col[e + 5];
            int r6 = col[e + 6];
            int r7 = col[e + 7];
            uint2 u0 = xs[(r0 << 4) + c];
            uint2 u1 = xs[(r1 << 4) + c];
            uint2 u2 = xs[(r2 << 4) + c];
            uint2 u3 = xs[(r3 << 4) + c];
            uint2 u4 = xs[(r4 << 4) + c];
            uint2 u5 = xs[(r5 << 4) + c];
            uint2 u6 = xs[(r6 << 4) + c];
            uint2 u7 = xs[(r7 << 4) + c];
            l0 = __hadd2(l0, *(const __half2*)&u0.x); h0 = __hadd2(h0, *(const __half2*)&u0.y);
            l1 = __hadd2(l1, *(const __half2*)&u1.x); h1 = __hadd2(h1, *(const __half2*)&u1.y);
            l2 = __hadd2(l2, *(const __half2*)&u2.x); h2 = __hadd2(h2, *(const __half2*)&u2.y);
            l3 = __hadd2(l3, *(const __half2*)&u3.x); h3 = __hadd2(h3, *(const __half2*)&u3.y);
            l0 = __hadd2(l0, *(const __half2*)&u4.x); h0 = __hadd2(h0, *(const __half2*)&u4.y);
            l1 = __hadd2(l1, *(const __half2*)&u5.x); h1 = __hadd2(h1, *(const __half2*)&u5.y);
            l2 = __hadd2(l2, *(const __half2*)&u6.x); h2 = __hadd2(h2, *(const __half2*)&u6.y);
            l3 = __hadd2(l3, *(const __half2*)&u7.x); h3 = __hadd2(h3, *(const __half2*)&u7.y);
        }
        for (; e + 3 < end; e += 4) {
            int r0 = col[e];
            int r1 = col[e + 1];
            int r2 = col[e + 2];
            int r3 = col[e + 3];
            uint2 u0 = xs[(r0 << 4) + c];
            uint2 u1 = xs[(r1 << 4) + c];
            uint2 u2 = xs[(r2 << 4) + c];
            uint2 u3 = xs[(r3 << 4) + c];
            l0 = __hadd2(l0, *(const __half2*)&u0.x); h0 = __hadd2(h0, *(const __half2*)&u0.y);
            l1 = __hadd2(l1, *(const __half2*)&u1.x); h1 = __hadd2(h1, *(const __half2*)&u1.y);
            l2 = __hadd2(l2, *(const __half2*)&u2.x); h2 = __hadd2(h2, *(const __half2*)&u2.y);
            l3 = __hadd2(l3, *(const __half2*)&u3.x); h3 = __hadd2(h3, *(const __half2*)&u3.y);
        }
        for (; e < end; ++e) {
            int r = col[e];
            uint2 u = xs[(r << 4) + c];
            l0 = __hadd2(l0, *(const __half2*)&u.x);
            h0 = __hadd2(h0, *(const __half2*)&u.y);
        }
        // combine the 4 fp16 partial streams in fp32, mean, convert to fp16
        float2 fl0 = __half22float2(l0), fl1 = __half22float2(l1);
        float2 fl2 = __half22float2(l2), fl3 = __half22float2(l3);
        float2 fh0 = __half22float2(h0), fh1 = __half22float2(h1);
        float2 fh2 = __half22float2(h2), fh3 = __half22float2(h3);
        float inv = 1.0f / fmaxf((float)(end - beg), 1.0f);
        half4_t hm;
        hm[0] = (_Float16)(((fl0.x + fl1.x) + (fl2.x + fl3.x)) * inv);
        hm[1] = (_Float16)(((fl0.y + fl1.y) + (fl2.y + fl3.y)) * inv);
        hm[2] = (_Float16)(((fh0.x + fh1.x) + (fh2.x + fh3.x)) * inv);
        hm[3] = (_Float16)(((fh0.y + fh1.y) + (fh2.y + fh3.y)) * inv);
        *((half4_t*)&smh[local][c << 2]) = hm;
        *((uint2*)&sxh[local][c << 2]) = xdu;      // root already fp16
    }
    __syncthreads();   // block-wide: epilogue waves read all 16 nodes

    // ---- MFMA epilogue: this wave computes cols [wave*16, wave*16+16) ----
    int fcol = (wave << 4) + (lane & 15);
    int g4 = lane >> 4;
    const half4_t* BL = (const half4_t*)wl16;
    const half4_t* BR = (const half4_t*)wr16;
    floatx4 acc = {0.f, 0.f, 0.f, 0.f};
#pragma unroll
    for (int ks = 0; ks < 4; ++ks) {
        int ko = (ks << 4) + (g4 << 2);
        half4_t am = *((const half4_t*)&smh[lane & 15][ko]);
        half4_t ax = *((const half4_t*)&sxh[lane & 15][ko]);
        half4_t bw_l = BL[((ks << 2) + g4) * 64 + fcol];
        half4_t bw_r = BR[((ks << 2) + g4) * 64 + fcol];
        acc = __builtin_amdgcn_mfma_f32_16x16x16f16(am, bw_l, acc, 0, 0, 0);
        acc = __builtin_amdgcn_mfma_f32_16x16x16f16(ax, bw_r, acc, 0, 0, 0);
    }
    float bb = bl[fcol];
    int nb0 = bid * 16 + (g4 << 2);   // D row = node local = g4*4 + j
#pragma unroll
    for (int j = 0; j < 4; ++j) {
        int n2 = nb0 + j;
        if (n2 < n_dst) {
            float v = acc[j] + bb;
            if (RELU) v = fmaxf(v, 0.f);
            outh[(size_t)n2 * H + fcol] = __float2half(v);
        }
    }
}

// ---------- classifier: 2 edges per 16-lane group (fp16 features, fp32 dot) ----------
__global__ __launch_bounds__(256) void k_dot(const __half* __restrict__ xu,
                                             const __half* __restrict__ xr,
                                             const int* __restrict__ eli,
                                             float* __restrict__ out, int L) {
    long long wv = (blockIdx.x * 256LL + threadIdx.x) >> 6;
    int lane = threadIdx.x & 63;
    int c = lane & 15, g = lane >> 4;
    long long e0 = wv * 8 + (long long)g * 2;
    if (e0 >= L) return;
    bool two = (e0 + 1 < L);
    int a0 = eli[e0];
    int b0 = eli[(long long)L + e0];
    int a1 = two ? eli[e0 + 1] : a0;
    int b1 = two ? eli[(long long)L + e0 + 1] : b0;
    const uint2* XU = (const uint2*)xu;
    const uint2* XR = (const uint2*)xr;
    uint2 u0 = XU[(a0 << 4) + c];
    uint2 r0 = XR[(b0 << 4) + c];
    uint2 u1 = XU[(a1 << 4) + c];
    uint2 r1 = XR[(b1 << 4) + c];
    float2 ua = __half22float2(*(const __half2*)&u0.x), ub = __half22float2(*(const __half2*)&u0.y);
    float2 ra = __half22float2(*(const __half2*)&r0.x), rb = __half22float2(*(const __half2*)&r0.y);
    float2 va = __half22float2(*(const __half2*)&u1.x), vb = __half22float2(*(const __half2*)&u1.y);
    float2 sa = __half22float2(*(const __half2*)&r1.x), sb = __half22float2(*(const __half2*)&r1.y);
    float p0 = ua.x * ra.x; p0 = fmaf(ua.y, ra.y, p0); p0 = fmaf(ub.x, rb.x, p0); p0 = fmaf(ub.y, rb.y, p0);
    float p1 = va.x * sa.x; p1 = fmaf(va.y, sa.y, p1); p1 = fmaf(vb.x, sb.x, p1); p1 = fmaf(vb.y, sb.y, p1);
#pragma unroll
    for (int off = 1; off < 16; off <<= 1) {
        p0 += __shfl_xor(p0, off);
        p1 += __shfl_xor(p1, off);
    }
    if (c == 0) {
        out[e0] = p0;
        if (two) out[e0 + 1] = p1;
    }
}

extern "C" void kernel_launch(void* const* d_in, const int* in_sizes, int n_in,
                              void* d_out, int out_size, void* d_ws, size_t ws_size,
                              hipStream_t stream) {
    const int*   uid        = (const int*)d_in[0];
    const int*   rid        = (const int*)d_in[1];
    const float* recipe_x   = (const float*)d_in[2];
    const int*   ei         = (const int*)d_in[3];
    const int*   eli        = (const int*)d_in[4];
    const float* user_emb   = (const float*)d_in[5];
    const float* recipe_emb = (const float*)d_in[6];
    const float* lin_w      = (const float*)d_in[7];
    const float* lin_b      = (const float*)d_in[8];
    const float* Wl         = (const float*)d_in[9];
    const float* bl         = (const float*)d_in[10];
    const float* Wr         = (const float*)d_in[11];

    const int Nu = in_sizes[0], Nr = in_sizes[1];
    const int E = in_sizes[3] / 2, L = in_sizes[4] / 2;
    const int nmax = (Nu > Nr) ? Nu : Nr;
    const int W = ((nmax - 1) >> WSH) + 1;   // 196 for N=200000

    char* ws = (char*)d_ws;
    size_t off = 0;
    auto alloc = [&](size_t bytes) -> char* {
        char* p = ws + off;
        off += (bytes + 255) & ~(size_t)255;
        return p;
    };
    // overlay region: bin buffers (dead after k_scat) share space with the
    // fp16 feature arrays [xh | yh] (~138MB total footprint).
    size_t hbytes = ((size_t)Nu + Nr) * H * 2;            // one fp16 feature set
    size_t bbytes = (size_t)E * 8 * 2;                    // bufS,bufD
    size_t rbytes = 2 * hbytes;                           // xh + yh = 102.4MB
    char* region  = alloc(rbytes > bbytes ? rbytes : bbytes);
    __half* xh_user   = (__half*)region;                  // init feats; layer-1 out
    __half* xh_recipe = (__half*)(region + (size_t)Nu * H * 2);
    __half* yh_user   = (__half*)(region + hbytes);       // layer-0 out
    __half* yh_recipe = (__half*)(region + hbytes + (size_t)Nu * H * 2);
    int2* bufS = (int2*)region;
    int2* bufD = (int2*)(region + (size_t)E * 8);
    int* rp_src  = (int*)alloc((size_t)(Nu + 1) * 4);
    int* rp_dst  = (int*)alloc((size_t)(Nr + 1) * 4);
    int* col_src = (int*)alloc((size_t)E * 4);
    int* col_dst = (int*)alloc((size_t)E * 4);
    // zero block: winS, winD, deg_src, deg_dst contiguous -> one memset
    int* winS    = (int*)alloc(MAXW * 4);
    int* winD    = (int*)alloc(MAXW * 4);
    int* deg_src = (int*)alloc((size_t)Nu * 4);
    int* deg_dst = (int*)alloc((size_t)Nr * 4);
    char* zend   = ws + off;
    int* baseS = (int*)alloc((MAXW + 1) * 4);
    int* baseD = (int*)alloc((MAXW + 1) * 4);
    int* curS  = (int*)alloc(MAXW * 4);
    int* curD  = (int*)alloc(MAXW * 4);
    _Float16* w16 = (_Float16*)alloc(8 * 4096 * 2);       // fp16 fragment-order weights
    (void)ws_size; (void)n_in; (void)out_size;

    // zero window + degree counters (ws is poisoned 0xAA)
    hipMemsetAsync(winS, 0, (size_t)(zend - (char*)winS), stream);

    // CSR build: count -> scan -> bin(+deg) -> per-window scan+scatter
    k_wincount<<<1024, 256, 0, stream>>>(ei, E, winS, winD);
    k_scan_win<<<1, 256, 0, stream>>>(winS, winD, baseS, baseD, curS, curD);
    k_bin<<<(E + BINCH - 1) / BINCH, 256, 0, stream>>>(ei, E, curS, curD,
                                                       deg_src, deg_dst, bufS, bufD);
    k_scat<<<2 * W, 256, 0, stream>>>(bufS, bufD, baseS, baseD, deg_src, deg_dst,
                                      rp_src, rp_dst, col_src, col_dst, Nu, Nr, W);

    // weights -> fp16 fragment order; initial features (fp16 only; bufs dead)
    k_prep_w<<<128, 256, 0, stream>>>(Wl, Wr, w16);
    k_init_x<<<(nmax + 3) / 4, 256, 0, stream>>>(uid, rid, recipe_x, user_emb, recipe_emb,
                                                 lin_w, lin_b, xh_user, xh_recipe, Nu, Nr);

    int nbR = (Nr + 15) / 16, nbU = (Nu + 15) / 16;
    // w16 matrix m = layer*4 + rel*2 + lr, each 4096 elements
    // layer 0 (+ReLU): gather xh, root xh; out yh
    k_sage3<true><<<nbR + nbU, 256, 0, stream>>>(
        xh_user, xh_recipe, rp_dst, col_dst, w16 + 0 * 4096, w16 + 1 * 4096,
        bl + 0 * H, yh_recipe, Nr, nbR,
        xh_recipe, xh_user, rp_src, col_src, w16 + 2 * 4096, w16 + 3 * 4096,
        bl + 1 * H, yh_user, Nu);
    // layer 1 (no ReLU): gather yh, root yh; out xh (classifier input)
    k_sage3<false><<<nbR + nbU, 256, 0, stream>>>(
        yh_user, yh_recipe, rp_dst, col_dst, w16 + 4 * 4096, w16 + 5 * 4096,
        bl + 2 * H, xh_recipe, Nr, nbR,
        yh_recipe, yh_user, rp_src, col_src, w16 + 6 * 4096, w16 + 7 * 4096,
        bl + 3 * H, xh_user, Nu);

    // classifier: 32 edges per block
    long long nblk = ((long long)L + 31) / 32;
    k_dot<<<(int)nblk, 256, 0, stream>>>(xh_user, xh_recipe, eli, (float*)d_out, L);
}

// Round 11
// 732.458 us; speedup vs baseline: 1.4048x; 1.4048x over previous
//
#include <hip/hip_runtime.h>
#include <hip/hip_fp16.h>

#define H 64
#define MAXW 256        // max windows (scan width)
#define WSH 10          // 1024 nodes per window -> W = ceil(200000/1024) = 196 <= MAXW
#define WNODES (1 << WSH)
#define BINCH 4096      // edges per k_bin block
#define BPT (BINCH / 256)
#define BCAP 24576      // buf slots per window (mean 20480, sigma~143 -> 28-sigma slack)

typedef _Float16 half4_t __attribute__((ext_vector_type(4)));
typedef float floatx4 __attribute__((ext_vector_type(4)));

// ---------- window cursor init: cur[w] = w * BCAP (replaces k_wincount+memset) ----------
__global__ void k_init_cur(int* __restrict__ curS, int* __restrict__ curD) {
    int t = threadIdx.x;
    curS[t] = t * BCAP;
    curD[t] = t * BCAP;
}

// ---------- bin: LDS counting-sort of a 4096-edge chunk by window ----------
// ei read ONCE (dir1 swaps the same registers); no wid[] (flush recomputes
// w = rec.x>>WSH). Destination buf is SLACK-ALLOCATED (BCAP/window) so no
// count prepass is needed. NO global per-node atomics: R10 measured 16M
// scattered atomicAdds as ~255MB of near-memory RMW write-through (per-XCD
// L2s aren't coherent, so device-scope atomics bypass them) -> 330us. All
// histogramming stays in LDS.
__global__ __launch_bounds__(256) void k_bin(const int* __restrict__ ei, int E,
                                             int* __restrict__ gcurS, int* __restrict__ gcurD,
                                             int2* __restrict__ bufS, int2* __restrict__ bufD) {
    __shared__ int hist[MAXW];
    __shared__ int lbase[MAXW];
    __shared__ int lcur[MAXW];
    __shared__ int gdelta[MAXW];
    __shared__ int2 rec[BINCH];
    __shared__ int sscan[256];

    int tid = threadIdx.x;
    int e0 = blockIdx.x * BINCH;
    int n = min(BINCH, E - e0);

    int aa[BPT], bb[BPT];
#pragma unroll
    for (int j = 0; j < BPT; ++j) {
        int idx = tid + j * 256;
        if (idx < n) {
            aa[j] = ei[e0 + idx];
            bb[j] = ei[E + e0 + idx];
        }
    }

    for (int dir = 0; dir < 2; ++dir) {
        int* gcur = dir ? gcurD : gcurS;
        int2* buf = dir ? bufD : bufS;
        hist[tid] = 0;
        __syncthreads();
#pragma unroll
        for (int j = 0; j < BPT; ++j) {
            int idx = tid + j * 256;
            if (idx < n) {
                int k = dir ? bb[j] : aa[j];
                atomicAdd(&hist[k >> WSH], 1);
            }
        }
        __syncthreads();
        {   // exclusive scan of hist
            int hv = hist[tid];
            sscan[tid] = hv; __syncthreads();
            for (int off = 1; off < 256; off <<= 1) {
                int t = (tid >= off) ? sscan[tid - off] : 0; __syncthreads();
                sscan[tid] += t; __syncthreads();
            }
            lbase[tid] = sscan[tid] - hv;
            lcur[tid] = lbase[tid];
        }
        __syncthreads();
#pragma unroll
        for (int j = 0; j < BPT; ++j) {
            int idx = tid + j * 256;
            if (idx < n) {
                int k = dir ? bb[j] : aa[j];
                int v = dir ? aa[j] : bb[j];
                int w = k >> WSH;
                int p = atomicAdd(&lcur[w], 1);
                rec[p] = make_int2(k, v);
            }
        }
        __syncthreads();
        {   // reserve one contiguous chunk in the window's slack region
            int c = hist[tid];
            int g = c ? atomicAdd(&gcur[tid], c) : 0;
            gdelta[tid] = g - lbase[tid];
        }
        __syncthreads();
        for (int j = tid; j < n; j += 256) {   // coalesced flush (runs sorted by window)
            int2 r = rec[j];
            int w = r.x >> WSH;
            *(long long*)&buf[gdelta[w] + j] = *(long long*)&r;
        }
        __syncthreads();
    }
}

// ---------- window-count scan: counts from post-bin cursors -> compact col bases ----------
__global__ void k_scan_win2(const int* __restrict__ curS, const int* __restrict__ curD,
                            int* __restrict__ baseS, int* __restrict__ baseD) {
    __shared__ int s[256];
    int tid = threadIdx.x;
    int v = curS[tid] - tid * BCAP;
    s[tid] = v; __syncthreads();
    for (int off = 1; off < 256; off <<= 1) {
        int t = (tid >= off) ? s[tid - off] : 0; __syncthreads();
        s[tid] += t; __syncthreads();
    }
    baseS[tid] = s[tid] - v;
    if (tid == 255) baseS[256] = s[255];
    __syncthreads();
    v = curD[tid] - tid * BCAP;
    s[tid] = v; __syncthreads();
    for (int off = 1; off < 256; off <<= 1) {
        int t = (tid >= off) ? s[tid - off] : 0; __syncthreads();
        s[tid] += t; __syncthreads();
    }
    baseD[tid] = s[tid] - v;
    if (tid == 255) baseD[256] = s[255];
}

// ---------- fused per-window CSR build: LDS histogram -> scan -> rp -> scatter ----------
// R9's proven structure; reads buf from the slacked layout [w*BCAP, cur[w]),
// writes compact rp/col at base[w].
__global__ __launch_bounds__(256) void k_build_win(const int2* __restrict__ bufS,
                                                   const int2* __restrict__ bufD,
                                                   const int* __restrict__ curS,
                                                   const int* __restrict__ curD,
                                                   const int* __restrict__ baseS,
                                                   const int* __restrict__ baseD,
                                                   int* __restrict__ rpS, int* __restrict__ rpD,
                                                   int* __restrict__ colS, int* __restrict__ colD,
                                                   int Ns, int Nd, int W) {
    __shared__ int h[WNODES];
    __shared__ int sscan[256];
    int b = blockIdx.x, tid = threadIdx.x;
    int dir = (b >= W) ? 1 : 0;
    int w = dir ? b - W : b;
    const int2* buf = dir ? bufD : bufS;
    const int* cur = dir ? curD : curS;
    const int* base = dir ? baseD : baseS;
    int* rp = dir ? rpD : rpS;
    int* col = dir ? colD : colS;
    int N = dir ? Nd : Ns;
    int lo = w << WSH;
    int hi = min(lo + WNODES, N);
    int bufbeg = w * BCAP, bufend = cur[w];
    int beg = base[w];                       // compact col base

    for (int i = tid; i < WNODES; i += 256) h[i] = 0;
    __syncthreads();
    for (int r = bufbeg + tid; r < bufend; r += 256)
        atomicAdd(&h[buf[r].x - lo], 1);
    __syncthreads();

    // exclusive scan of h[0..1023] (4 elems/thread + 256-wide LDS scan)
    int i0 = tid * 4;
    int v0 = h[i0], v1 = h[i0 + 1], v2 = h[i0 + 2], v3 = h[i0 + 3];
    int t = v0 + v1 + v2 + v3;
    sscan[tid] = t; __syncthreads();
    for (int off = 1; off < 256; off <<= 1) {
        int x = (tid >= off) ? sscan[tid - off] : 0; __syncthreads();
        sscan[tid] += x; __syncthreads();
    }
    int e0 = sscan[tid] - t;
    int e1 = e0 + v0, e2 = e1 + v1, e3 = e2 + v2;
    h[i0] = e0; h[i0 + 1] = e1; h[i0 + 2] = e2; h[i0 + 3] = e3;  // cursors
    int gi = lo + i0;
    if (gi < hi) rp[gi] = beg + e0;
    if (gi + 1 < hi) rp[gi + 1] = beg + e1;
    if (gi + 2 < hi) rp[gi + 2] = beg + e2;
    if (gi + 3 < hi) rp[gi + 3] = beg + e3;
    if (tid == 255 && hi == N) rp[N] = beg + sscan[255];
    __syncthreads();

    for (int r = bufbeg + tid; r < bufend; r += 256) {
        int2 rc = buf[r];
        int p = atomicAdd(&h[rc.x - lo], 1);
        col[beg + p] = rc.y;
    }
}

// ---------- weight prep: fp32 [layer][rel][64][64] -> fp16 MFMA-fragment order ----------
__global__ __launch_bounds__(256) void k_prep_w(const float* __restrict__ Wl,
                                                const float* __restrict__ Wr,
                                                _Float16* __restrict__ w16) {
    int gid = blockIdx.x * 256 + threadIdx.x;     // 8 * 4096 = 32768
    int m = gid >> 12;
    int o = gid & 4095;
    int ks = o >> 10, g4 = (o >> 8) & 3, col = (o >> 2) & 63, j = o & 3;
    int k = (ks << 4) + (g4 << 2) + j;
    int lr = m & 1, rel = (m >> 1) & 1, layer = m >> 2;
    const float* Wsrc = lr ? Wr : Wl;
    w16[gid] = (_Float16)Wsrc[((layer * 2 + rel) * 64 + k) * 64 + col];
}

// ---------- feature init: fp16-only features ----------
__global__ __launch_bounds__(256) void k_init_x(const int* __restrict__ uid, const int* __restrict__ rid,
                         const float* __restrict__ recipe_x,
                         const float* __restrict__ user_emb, const float* __restrict__ recipe_emb,
                         const float* __restrict__ lin_w, const float* __restrict__ lin_b,
                         __half* __restrict__ xh_user, __half* __restrict__ xh_recipe,
                         int Nu, int Nr) {
    int n = blockIdx.x * 4 + (threadIdx.x >> 6);
    int h = threadIdx.x & 63;
    if (n < Nr) {
        float o = lin_b[h];
#pragma unroll
        for (int k = 0; k < 10; ++k)   // recipe_x addr wave-uniform -> broadcast load
            o = fmaf(recipe_x[(size_t)n * 10 + k], lin_w[k * H + h], o);
        o += recipe_emb[(size_t)rid[n] * H + h];
        xh_recipe[(size_t)n * H + h] = __float2half(o);
    }
    if (n < Nu) {
        xh_user[(size_t)n * H + h] = __float2half(user_emb[(size_t)uid[n] * H + h]);
    }
}

// ---------- SAGE layer: fp16 gather + MFMA epilogue (unchanged from R9) ----------
template <bool RELU>
__global__ __launch_bounds__(256, 6) void k_sage3(
    const __half* __restrict__ gsA, const __half* __restrict__ rtA,
    const int* __restrict__ rpA, const int* __restrict__ colA,
    const _Float16* __restrict__ wlA, const _Float16* __restrict__ wrA,
    const float* __restrict__ blA, __half* __restrict__ outA, int ndA, int nbA,
    const __half* __restrict__ gsB, const __half* __restrict__ rtB,
    const int* __restrict__ rpB, const int* __restrict__ colB,
    const _Float16* __restrict__ wlB, const _Float16* __restrict__ wrB,
    const float* __restrict__ blB, __half* __restrict__ outB, int ndB) {
    const __half* gs; const __half* rt; const int* rp; const int* col;
    const _Float16* wl16; const _Float16* wr16; const float* bl; __half* outh;
    int n_dst, bid;
    if (blockIdx.x < (unsigned)nbA) {
        gs = gsA; rt = rtA; rp = rpA; col = colA;
        wl16 = wlA; wr16 = wrA; bl = blA; outh = outA; n_dst = ndA; bid = blockIdx.x;
    } else {
        gs = gsB; rt = rtB; rp = rpB; col = colB;
        wl16 = wlB; wr16 = wrB; bl = blB; outh = outB; n_dst = ndB; bid = blockIdx.x - nbA;
    }

    int wave = threadIdx.x >> 6, lane = threadIdx.x & 63;
    int c = lane & 15, g = lane >> 4;          // group g owns node local=wave*4+g
    __shared__ __align__(16) _Float16 smh[16][72];   // [node][feat] mean, stride 72
    __shared__ __align__(16) _Float16 sxh[16][72];   // [node][feat] root

    int local = (wave << 2) + g;
    int n = bid * 16 + local;
    if (n < n_dst) {
        const uint2* xs = (const uint2*)gs;    // fp16 row = 128B = 16 x uint2
        uint2 xdu = ((const uint2*)rt)[(n << 4) + c];   // root row, overlaps gather
        int beg = rp[n], end = rp[n + 1];
        __half2 z = __float2half2_rn(0.f);
        __half2 l0 = z, l1 = z, l2 = z, l3 = z;   // lo pair (features 4c, 4c+1)
        __half2 h0 = z, h1 = z, h2 = z, h3 = z;   // hi pair (features 4c+2, 4c+3)
        int e = beg;
        for (; e + 7 < end; e += 8) {           // 8 loads in flight per group
            int r0 = col[e];
            int r1 = col[e + 1];
            int r2 = col[e + 2];
            int r3 = col[e + 3];
            int r4 = col[e + 4];
            int r5 = col[e + 5];
            int r6 = col[e + 6];
            int r7 = col[e + 7];
            uint2 u0 = xs[(r0 << 4) + c];
            uint2 u1 = xs[(r1 << 4) + c];
            uint2 u2 = xs[(r2 << 4) + c];
            uint2 u3 = xs[(r3 << 4) + c];
            uint2 u4 = xs[(r4 << 4) + c];
            uint2 u5 = xs[(r5 << 4) + c];
            uint2 u6 = xs[(r6 << 4) + c];
            uint2 u7 = xs[(r7 << 4) + c];
            l0 = __hadd2(l0, *(const __half2*)&u0.x); h0 = __hadd2(h0, *(const __half2*)&u0.y);
            l1 = __hadd2(l1, *(const __half2*)&u1.x); h1 = __hadd2(h1, *(const __half2*)&u1.y);
            l2 = __hadd2(l2, *(const __half2*)&u2.x); h2 = __hadd2(h2, *(const __half2*)&u2.y);
            l3 = __hadd2(l3, *(const __half2*)&u3.x); h3 = __hadd2(h3, *(const __half2*)&u3.y);
            l0 = __hadd2(l0, *(const __half2*)&u4.x); h0 = __hadd2(h0, *(const __half2*)&u4.y);
            l1 = __hadd2(l1, *(const __half2*)&u5.x); h1 = __hadd2(h1, *(const __half2*)&u5.y);
            l2 = __hadd2(l2, *(const __half2*)&u6.x); h2 = __hadd2(h2, *(const __half2*)&u6.y);
            l3 = __hadd2(l3, *(const __half2*)&u7.x); h3 = __hadd2(h3, *(const __half2*)&u7.y);
        }
        for (; e + 3 < end; e += 4) {
            int r0 = col[e];
            int r1 = col[e + 1];
            int r2 = col[e + 2];
            int r3 = col[e + 3];
            uint2 u0 = xs[(r0 << 4) + c];
            uint2 u1 = xs[(r1 << 4) + c];
            uint2 u2 = xs[(r2 << 4) + c];
            uint2 u3 = xs[(r3 << 4) + c];
            l0 = __hadd2(l0, *(const __half2*)&u0.x); h0 = __hadd2(h0, *(const __half2*)&u0.y);
            l1 = __hadd2(l1, *(const __half2*)&u1.x); h1 = __hadd2(h1, *(const __half2*)&u1.y);
            l2 = __hadd2(l2, *(const __half2*)&u2.x); h2 = __hadd2(h2, *(const __half2*)&u2.y);
            l3 = __hadd2(l3, *(const __half2*)&u3.x); h3 = __hadd2(h3, *(const __half2*)&u3.y);
        }
        for (; e < end; ++e) {
            int r = col[e];
            uint2 u = xs[(r << 4) + c];
            l0 = __hadd2(l0, *(const __half2*)&u.x);
            h0 = __hadd2(h0, *(const __half2*)&u.y);
        }
        // combine the 4 fp16 partial streams in fp32, mean, convert to fp16
        float2 fl0 = __half22float2(l0), fl1 = __half22float2(l1);
        float2 fl2 = __half22float2(l2), fl3 = __half22float2(l3);
        float2 fh0 = __half22float2(h0), fh1 = __half22float2(h1);
        float2 fh2 = __half22float2(h2), fh3 = __half22float2(h3);
        float inv = 1.0f / fmaxf((float)(end - beg), 1.0f);
        half4_t hm;
        hm[0] = (_Float16)(((fl0.x + fl1.x) + (fl2.x + fl3.x)) * inv);
        hm[1] = (_Float16)(((fl0.y + fl1.y) + (fl2.y + fl3.y)) * inv);
        hm[2] = (_Float16)(((fh0.x + fh1.x) + (fh2.x + fh3.x)) * inv);
        hm[3] = (_Float16)(((fh0.y + fh1.y) + (fh2.y + fh3.y)) * inv);
        *((half4_t*)&smh[local][c << 2]) = hm;
        *((uint2*)&sxh[local][c << 2]) = xdu;      // root already fp16
    }
    __syncthreads();   // block-wide: epilogue waves read all 16 nodes

    // ---- MFMA epilogue: this wave computes cols [wave*16, wave*16+16) ----
    int fcol = (wave << 4) + (lane & 15);
    int g4 = lane >> 4;
    const half4_t* BL = (const half4_t*)wl16;
    const half4_t* BR = (const half4_t*)wr16;
    floatx4 acc = {0.f, 0.f, 0.f, 0.f};
#pragma unroll
    for (int ks = 0; ks < 4; ++ks) {
        int ko = (ks << 4) + (g4 << 2);
        half4_t am = *((const half4_t*)&smh[lane & 15][ko]);
        half4_t ax = *((const half4_t*)&sxh[lane & 15][ko]);
        half4_t bw_l = BL[((ks << 2) + g4) * 64 + fcol];
        half4_t bw_r = BR[((ks << 2) + g4) * 64 + fcol];
        acc = __builtin_amdgcn_mfma_f32_16x16x16f16(am, bw_l, acc, 0, 0, 0);
        acc = __builtin_amdgcn_mfma_f32_16x16x16f16(ax, bw_r, acc, 0, 0, 0);
    }
    float bb = bl[fcol];
    int nb0 = bid * 16 + (g4 << 2);   // D row = node local = g4*4 + j
#pragma unroll
    for (int j = 0; j < 4; ++j) {
        int n2 = nb0 + j;
        if (n2 < n_dst) {
            float v = acc[j] + bb;
            if (RELU) v = fmaxf(v, 0.f);
            outh[(size_t)n2 * H + fcol] = __float2half(v);
        }
    }
}

// ---------- classifier: 2 edges per 16-lane group (fp16 features, fp32 dot) ----------
__global__ __launch_bounds__(256) void k_dot(const __half* __restrict__ xu,
                                             const __half* __restrict__ xr,
                                             const int* __restrict__ eli,
                                             float* __restrict__ out, int L) {
    long long wv = (blockIdx.x * 256LL + threadIdx.x) >> 6;
    int lane = threadIdx.x & 63;
    int c = lane & 15, g = lane >> 4;
    long long e0 = wv * 8 + (long long)g * 2;
    if (e0 >= L) return;
    bool two = (e0 + 1 < L);
    int a0 = eli[e0];
    int b0 = eli[(long long)L + e0];
    int a1 = two ? eli[e0 + 1] : a0;
    int b1 = two ? eli[(long long)L + e0 + 1] : b0;
    const uint2* XU = (const uint2*)xu;
    const uint2* XR = (const uint2*)xr;
    uint2 u0 = XU[(a0 << 4) + c];
    uint2 r0 = XR[(b0 << 4) + c];
    uint2 u1 = XU[(a1 << 4) + c];
    uint2 r1 = XR[(b1 << 4) + c];
    float2 ua = __half22float2(*(const __half2*)&u0.x), ub = __half22float2(*(const __half2*)&u0.y);
    float2 ra = __half22float2(*(const __half2*)&r0.x), rb = __half22float2(*(const __half2*)&r0.y);
    float2 va = __half22float2(*(const __half2*)&u1.x), vb = __half22float2(*(const __half2*)&u1.y);
    float2 sa = __half22float2(*(const __half2*)&r1.x), sb = __half22float2(*(const __half2*)&r1.y);
    float p0 = ua.x * ra.x; p0 = fmaf(ua.y, ra.y, p0); p0 = fmaf(ub.x, rb.x, p0); p0 = fmaf(ub.y, rb.y, p0);
    float p1 = va.x * sa.x; p1 = fmaf(va.y, sa.y, p1); p1 = fmaf(vb.x, sb.x, p1); p1 = fmaf(vb.y, sb.y, p1);
#pragma unroll
    for (int off = 1; off < 16; off <<= 1) {
        p0 += __shfl_xor(p0, off);
        p1 += __shfl_xor(p1, off);
    }
    if (c == 0) {
        out[e0] = p0;
        if (two) out[e0 + 1] = p1;
    }
}

extern "C" void kernel_launch(void* const* d_in, const int* in_sizes, int n_in,
                              void* d_out, int out_size, void* d_ws, size_t ws_size,
                              hipStream_t stream) {
    const int*   uid        = (const int*)d_in[0];
    const int*   rid        = (const int*)d_in[1];
    const float* recipe_x   = (const float*)d_in[2];
    const int*   ei         = (const int*)d_in[3];
    const int*   eli        = (const int*)d_in[4];
    const float* user_emb   = (const float*)d_in[5];
    const float* recipe_emb = (const float*)d_in[6];
    const float* lin_w      = (const float*)d_in[7];
    const float* lin_b      = (const float*)d_in[8];
    const float* Wl         = (const float*)d_in[9];
    const float* bl         = (const float*)d_in[10];
    const float* Wr         = (const float*)d_in[11];

    const int Nu = in_sizes[0], Nr = in_sizes[1];
    const int E = in_sizes[3] / 2, L = in_sizes[4] / 2;
    const int nmax = (Nu > Nr) ? Nu : Nr;
    const int W = ((nmax - 1) >> WSH) + 1;   // 196 for N=200000

    char* ws = (char*)d_ws;
    size_t off = 0;
    auto alloc = [&](size_t bytes) -> char* {
        char* p = ws + off;
        off += (bytes + 255) & ~(size_t)255;
        return p;
    };
    // overlay region: slacked bin buffers (dead after k_build_win) share space
    // with the fp16 feature arrays [xh | yh]. Slack bufs = 2*196*BCAP*8 = 77MB
    // <= xh+yh = 102.4MB. Total ws footprint ~113MB.
    size_t hbytes = ((size_t)Nu + Nr) * H * 2;            // one fp16 feature set
    size_t bbytes = (size_t)2 * MAXW * BCAP * 8;          // slacked bufS,bufD
    size_t rbytes = 2 * hbytes;                           // xh + yh
    char* region  = alloc(rbytes > bbytes ? rbytes : bbytes);
    __half* xh_user   = (__half*)region;                  // init feats; layer-1 out
    __half* xh_recipe = (__half*)(region + (size_t)Nu * H * 2);
    __half* yh_user   = (__half*)(region + hbytes);       // layer-0 out
    __half* yh_recipe = (__half*)(region + hbytes + (size_t)Nu * H * 2);
    int2* bufS = (int2*)region;
    int2* bufD = (int2*)(region + (size_t)MAXW * BCAP * 8);
    int* rp_src  = (int*)alloc((size_t)(Nu + 1) * 4);
    int* rp_dst  = (int*)alloc((size_t)(Nr + 1) * 4);
    int* col_src = (int*)alloc((size_t)E * 4);
    int* col_dst = (int*)alloc((size_t)E * 4);
    int* baseS = (int*)alloc((MAXW + 1) * 4);
    int* baseD = (int*)alloc((MAXW + 1) * 4);
    int* curS  = (int*)alloc(MAXW * 4);
    int* curD  = (int*)alloc(MAXW * 4);
    _Float16* w16 = (_Float16*)alloc(8 * 4096 * 2);       // fp16 fragment-order weights
    (void)ws_size; (void)n_in; (void)out_size;

    // CSR build: cursor-init -> bin (single ei pass, slack buf) -> count scan
    // -> per-window hist+scan+scatter. No memsets, no count prepass.
    k_init_cur<<<1, 256, 0, stream>>>(curS, curD);
    k_bin<<<(E + BINCH - 1) / BINCH, 256, 0, stream>>>(ei, E, curS, curD, bufS, bufD);
    k_scan_win2<<<1, 256, 0, stream>>>(curS, curD, baseS, baseD);
    k_build_win<<<2 * W, 256, 0, stream>>>(bufS, bufD, curS, curD, baseS, baseD,
                                           rp_src, rp_dst, col_src, col_dst, Nu, Nr, W);

    // weights -> fp16 fragment order; initial features (fp16 only; bufs dead)
    k_prep_w<<<128, 256, 0, stream>>>(Wl, Wr, w16);
    k_init_x<<<(nmax + 3) / 4, 256, 0, stream>>>(uid, rid, recipe_x, user_emb, recipe_emb,
                                                 lin_w, lin_b, xh_user, xh_recipe, Nu, Nr);

    int nbR = (Nr + 15) / 16, nbU = (Nu + 15) / 16;
    // w16 matrix m = layer*4 + rel*2 + lr, each 4096 elements
    // layer 0 (+ReLU): gather xh, root xh; out yh
    k_sage3<true><<<nbR + nbU, 256, 0, stream>>>(
        xh_user, xh_recipe, rp_dst, col_dst, w16 + 0 * 4096, w16 + 1 * 4096,
        bl + 0 * H, yh_recipe, Nr, nbR,
        xh_recipe, xh_user, rp_src, col_src, w16 + 2 * 4096, w16 + 3 * 4096,
        bl + 1 * H, yh_user, Nu);
    // layer 1 (no ReLU): gather yh, root yh; out xh (classifier input)
    k_sage3<false><<<nbR + nbU, 256, 0, stream>>>(
        yh_user, yh_recipe, rp_dst, col_dst, w16 + 4 * 4096, w16 + 5 * 4096,
        bl + 2 * H, xh_recipe, Nr, nbR,
        yh_recipe, yh_user, rp_src, col_src, w16 + 6 * 4096, w16 + 7 * 4096,
        bl + 3 * H, xh_user, Nu);

    // classifier: 32 edges per block
    long long nblk = ((long long)L + 31) / 32;
    k_dot<<<(int)nblk, 256, 0, stream>>>(xh_user, xh_recipe, eli, (float*)d_out, L);
}

// Round 12
// 720.302 us; speedup vs baseline: 1.4285x; 1.0169x over previous
//
#include <hip/hip_runtime.h>
#include <hip/hip_fp16.h>

#define H 64
#define MAXW 256        // max windows (scan width)
#define WSH 10          // 1024 nodes per window -> W = ceil(200000/1024) = 196 <= MAXW
#define WNODES (1 << WSH)
#define BINCH 4096      // edges per k_bin block
#define BPT (BINCH / 256)
#define BCAP 24576      // buf slots per window (mean 20480, sigma~143 -> 28-sigma slack)

typedef _Float16 half4_t __attribute__((ext_vector_type(4)));
typedef float floatx4 __attribute__((ext_vector_type(4)));

// ---------- window cursor init: cur[w] = w * BCAP ----------
__global__ void k_init_cur(int* __restrict__ curS, int* __restrict__ curD) {
    int t = threadIdx.x;
    curS[t] = t * BCAP;
    curD[t] = t * BCAP;
}

// ---------- bin: LDS counting-sort of a 4096-edge chunk by window ----------
// ei read ONCE (dir1 swaps the same registers); no wid[]; slack-allocated buf
// (BCAP/window) so no count prepass. All histogramming in LDS (R10: 16M
// scattered global atomicAdds = ~255MB near-memory RMW write-through, 330us).
__global__ __launch_bounds__(256) void k_bin(const int* __restrict__ ei, int E,
                                             int* __restrict__ gcurS, int* __restrict__ gcurD,
                                             int2* __restrict__ bufS, int2* __restrict__ bufD) {
    __shared__ int hist[MAXW];
    __shared__ int lbase[MAXW];
    __shared__ int lcur[MAXW];
    __shared__ int gdelta[MAXW];
    __shared__ int2 rec[BINCH];
    __shared__ int sscan[256];

    int tid = threadIdx.x;
    int e0 = blockIdx.x * BINCH;
    int n = min(BINCH, E - e0);

    int aa[BPT], bb[BPT];
#pragma unroll
    for (int j = 0; j < BPT; ++j) {
        int idx = tid + j * 256;
        if (idx < n) {
            aa[j] = ei[e0 + idx];
            bb[j] = ei[E + e0 + idx];
        }
    }

    for (int dir = 0; dir < 2; ++dir) {
        int* gcur = dir ? gcurD : gcurS;
        int2* buf = dir ? bufD : bufS;
        hist[tid] = 0;
        __syncthreads();
#pragma unroll
        for (int j = 0; j < BPT; ++j) {
            int idx = tid + j * 256;
            if (idx < n) {
                int k = dir ? bb[j] : aa[j];
                atomicAdd(&hist[k >> WSH], 1);
            }
        }
        __syncthreads();
        {   // exclusive scan of hist
            int hv = hist[tid];
            sscan[tid] = hv; __syncthreads();
            for (int off = 1; off < 256; off <<= 1) {
                int t = (tid >= off) ? sscan[tid - off] : 0; __syncthreads();
                sscan[tid] += t; __syncthreads();
            }
            lbase[tid] = sscan[tid] - hv;
            lcur[tid] = lbase[tid];
        }
        __syncthreads();
#pragma unroll
        for (int j = 0; j < BPT; ++j) {
            int idx = tid + j * 256;
            if (idx < n) {
                int k = dir ? bb[j] : aa[j];
                int v = dir ? aa[j] : bb[j];
                int w = k >> WSH;
                int p = atomicAdd(&lcur[w], 1);
                rec[p] = make_int2(k, v);
            }
        }
        __syncthreads();
        {   // reserve one contiguous chunk in the window's slack region
            int c = hist[tid];
            int g = c ? atomicAdd(&gcur[tid], c) : 0;
            gdelta[tid] = g - lbase[tid];
        }
        __syncthreads();
        for (int j = tid; j < n; j += 256) {   // coalesced flush (runs sorted by window)
            int2 r = rec[j];
            int w = r.x >> WSH;
            *(long long*)&buf[gdelta[w] + j] = *(long long*)&r;
        }
        __syncthreads();
    }
}

// ---------- window-count scan: counts from post-bin cursors -> compact col bases ----------
__global__ void k_scan_win2(const int* __restrict__ curS, const int* __restrict__ curD,
                            int* __restrict__ baseS, int* __restrict__ baseD) {
    __shared__ int s[256];
    int tid = threadIdx.x;
    int v = curS[tid] - tid * BCAP;
    s[tid] = v; __syncthreads();
    for (int off = 1; off < 256; off <<= 1) {
        int t = (tid >= off) ? s[tid - off] : 0; __syncthreads();
        s[tid] += t; __syncthreads();
    }
    baseS[tid] = s[tid] - v;
    if (tid == 255) baseS[256] = s[255];
    __syncthreads();
    v = curD[tid] - tid * BCAP;
    s[tid] = v; __syncthreads();
    for (int off = 1; off < 256; off <<= 1) {
        int t = (tid >= off) ? s[tid - off] : 0; __syncthreads();
        s[tid] += t; __syncthreads();
    }
    baseD[tid] = s[tid] - v;
    if (tid == 255) baseD[256] = s[255];
}

// ---------- fused per-window CSR build: LDS histogram -> scan -> rp -> scatter ----------
__global__ __launch_bounds__(256) void k_build_win(const int2* __restrict__ bufS,
                                                   const int2* __restrict__ bufD,
                                                   const int* __restrict__ curS,
                                                   const int* __restrict__ curD,
                                                   const int* __restrict__ baseS,
                                                   const int* __restrict__ baseD,
                                                   int* __restrict__ rpS, int* __restrict__ rpD,
                                                   int* __restrict__ colS, int* __restrict__ colD,
                                                   int Ns, int Nd, int W) {
    __shared__ int h[WNODES];
    __shared__ int sscan[256];
    int b = blockIdx.x, tid = threadIdx.x;
    int dir = (b >= W) ? 1 : 0;
    int w = dir ? b - W : b;
    const int2* buf = dir ? bufD : bufS;
    const int* cur = dir ? curD : curS;
    const int* base = dir ? baseD : baseS;
    int* rp = dir ? rpD : rpS;
    int* col = dir ? colD : colS;
    int N = dir ? Nd : Ns;
    int lo = w << WSH;
    int hi = min(lo + WNODES, N);
    int bufbeg = w * BCAP, bufend = cur[w];
    int beg = base[w];                       // compact col base

    for (int i = tid; i < WNODES; i += 256) h[i] = 0;
    __syncthreads();
    for (int r = bufbeg + tid; r < bufend; r += 256)
        atomicAdd(&h[buf[r].x - lo], 1);
    __syncthreads();

    // exclusive scan of h[0..1023] (4 elems/thread + 256-wide LDS scan)
    int i0 = tid * 4;
    int v0 = h[i0], v1 = h[i0 + 1], v2 = h[i0 + 2], v3 = h[i0 + 3];
    int t = v0 + v1 + v2 + v3;
    sscan[tid] = t; __syncthreads();
    for (int off = 1; off < 256; off <<= 1) {
        int x = (tid >= off) ? sscan[tid - off] : 0; __syncthreads();
        sscan[tid] += x; __syncthreads();
    }
    int e0 = sscan[tid] - t;
    int e1 = e0 + v0, e2 = e1 + v1, e3 = e2 + v2;
    h[i0] = e0; h[i0 + 1] = e1; h[i0 + 2] = e2; h[i0 + 3] = e3;  // cursors
    int gi = lo + i0;
    if (gi < hi) rp[gi] = beg + e0;
    if (gi + 1 < hi) rp[gi + 1] = beg + e1;
    if (gi + 2 < hi) rp[gi + 2] = beg + e2;
    if (gi + 3 < hi) rp[gi + 3] = beg + e3;
    if (tid == 255 && hi == N) rp[N] = beg + sscan[255];
    __syncthreads();

    for (int r = bufbeg + tid; r < bufend; r += 256) {
        int2 rc = buf[r];
        int p = atomicAdd(&h[rc.x - lo], 1);
        col[beg + p] = rc.y;
    }
}

// ---------- feature init (fp16-only) + fused weight prep ----------
// Blocks [0,128) additionally convert the 8x64x64 weights to fp16 MFMA
// fragment order: idx = ((ks*4+g4)*64 + col)*4 + j holds W[k=ks*16+g4*4+j][col];
// matrix m = layer*4 + rel*2 + lr (lr: 0=Wl, 1=Wr). Saves one dispatch.
__global__ __launch_bounds__(256) void k_init_x(const int* __restrict__ uid, const int* __restrict__ rid,
                         const float* __restrict__ recipe_x,
                         const float* __restrict__ user_emb, const float* __restrict__ recipe_emb,
                         const float* __restrict__ lin_w, const float* __restrict__ lin_b,
                         const float* __restrict__ Wl, const float* __restrict__ Wr,
                         _Float16* __restrict__ w16,
                         __half* __restrict__ xh_user, __half* __restrict__ xh_recipe,
                         int Nu, int Nr) {
    int gid = blockIdx.x * 256 + threadIdx.x;
    if (gid < 32768) {   // weight prep (first 128 blocks)
        int m = gid >> 12;
        int o = gid & 4095;
        int ks = o >> 10, g4 = (o >> 8) & 3, col = (o >> 2) & 63, j = o & 3;
        int k = (ks << 4) + (g4 << 2) + j;
        int lr = m & 1, rel = (m >> 1) & 1, layer = m >> 2;
        const float* Wsrc = lr ? Wr : Wl;
        w16[gid] = (_Float16)Wsrc[((layer * 2 + rel) * 64 + k) * 64 + col];
    }
    int n = blockIdx.x * 4 + (threadIdx.x >> 6);
    int h = threadIdx.x & 63;
    if (n < Nr) {
        float o = lin_b[h];
#pragma unroll
        for (int k = 0; k < 10; ++k)   // recipe_x addr wave-uniform -> broadcast load
            o = fmaf(recipe_x[(size_t)n * 10 + k], lin_w[k * H + h], o);
        o += recipe_emb[(size_t)rid[n] * H + h];
        xh_recipe[(size_t)n * H + h] = __float2half(o);
    }
    if (n < Nu) {
        xh_user[(size_t)n * H + h] = __float2half(user_emb[(size_t)uid[n] * H + h]);
    }
}

// ---------- SAGE layer: fp16 gather + MFMA epilogue (unchanged from R9/R11) ----------
template <bool RELU>
__global__ __launch_bounds__(256, 6) void k_sage3(
    const __half* __restrict__ gsA, const __half* __restrict__ rtA,
    const int* __restrict__ rpA, const int* __restrict__ colA,
    const _Float16* __restrict__ wlA, const _Float16* __restrict__ wrA,
    const float* __restrict__ blA, __half* __restrict__ outA, int ndA, int nbA,
    const __half* __restrict__ gsB, const __half* __restrict__ rtB,
    const int* __restrict__ rpB, const int* __restrict__ colB,
    const _Float16* __restrict__ wlB, const _Float16* __restrict__ wrB,
    const float* __restrict__ blB, __half* __restrict__ outB, int ndB) {
    const __half* gs; const __half* rt; const int* rp; const int* col;
    const _Float16* wl16; const _Float16* wr16; const float* bl; __half* outh;
    int n_dst, bid;
    if (blockIdx.x < (unsigned)nbA) {
        gs = gsA; rt = rtA; rp = rpA; col = colA;
        wl16 = wlA; wr16 = wrA; bl = blA; outh = outA; n_dst = ndA; bid = blockIdx.x;
    } else {
        gs = gsB; rt = rtB; rp = rpB; col = colB;
        wl16 = wlB; wr16 = wrB; bl = blB; outh = outB; n_dst = ndB; bid = blockIdx.x - nbA;
    }

    int wave = threadIdx.x >> 6, lane = threadIdx.x & 63;
    int c = lane & 15, g = lane >> 4;          // group g owns node local=wave*4+g
    __shared__ __align__(16) _Float16 smh[16][72];   // [node][feat] mean, stride 72
    __shared__ __align__(16) _Float16 sxh[16][72];   // [node][feat] root

    int local = (wave << 2) + g;
    int n = bid * 16 + local;
    if (n < n_dst) {
        const uint2* xs = (const uint2*)gs;    // fp16 row = 128B = 16 x uint2
        uint2 xdu = ((const uint2*)rt)[(n << 4) + c];   // root row, overlaps gather
        int beg = rp[n], end = rp[n + 1];
        __half2 z = __float2half2_rn(0.f);
        __half2 l0 = z, l1 = z, l2 = z, l3 = z;   // lo pair (features 4c, 4c+1)
        __half2 h0 = z, h1 = z, h2 = z, h3 = z;   // hi pair (features 4c+2, 4c+3)
        int e = beg;
        for (; e + 7 < end; e += 8) {           // 8 loads in flight per group
            int r0 = col[e];
            int r1 = col[e + 1];
            int r2 = col[e + 2];
            int r3 = col[e + 3];
            int r4 = col[e + 4];
            int r5 = col[e + 5];
            int r6 = col[e + 6];
            int r7 = col[e + 7];
            uint2 u0 = xs[(r0 << 4) + c];
            uint2 u1 = xs[(r1 << 4) + c];
            uint2 u2 = xs[(r2 << 4) + c];
            uint2 u3 = xs[(r3 << 4) + c];
            uint2 u4 = xs[(r4 << 4) + c];
            uint2 u5 = xs[(r5 << 4) + c];
            uint2 u6 = xs[(r6 << 4) + c];
            uint2 u7 = xs[(r7 << 4) + c];
            l0 = __hadd2(l0, *(const __half2*)&u0.x); h0 = __hadd2(h0, *(const __half2*)&u0.y);
            l1 = __hadd2(l1, *(const __half2*)&u1.x); h1 = __hadd2(h1, *(const __half2*)&u1.y);
            l2 = __hadd2(l2, *(const __half2*)&u2.x); h2 = __hadd2(h2, *(const __half2*)&u2.y);
            l3 = __hadd2(l3, *(const __half2*)&u3.x); h3 = __hadd2(h3, *(const __half2*)&u3.y);
            l0 = __hadd2(l0, *(const __half2*)&u4.x); h0 = __hadd2(h0, *(const __half2*)&u4.y);
            l1 = __hadd2(l1, *(const __half2*)&u5.x); h1 = __hadd2(h1, *(const __half2*)&u5.y);
            l2 = __hadd2(l2, *(const __half2*)&u6.x); h2 = __hadd2(h2, *(const __half2*)&u6.y);
            l3 = __hadd2(l3, *(const __half2*)&u7.x); h3 = __hadd2(h3, *(const __half2*)&u7.y);
        }
        for (; e + 3 < end; e += 4) {
            int r0 = col[e];
            int r1 = col[e + 1];
            int r2 = col[e + 2];
            int r3 = col[e + 3];
            uint2 u0 = xs[(r0 << 4) + c];
            uint2 u1 = xs[(r1 << 4) + c];
            uint2 u2 = xs[(r2 << 4) + c];
            uint2 u3 = xs[(r3 << 4) + c];
            l0 = __hadd2(l0, *(const __half2*)&u0.x); h0 = __hadd2(h0, *(const __half2*)&u0.y);
            l1 = __hadd2(l1, *(const __half2*)&u1.x); h1 = __hadd2(h1, *(const __half2*)&u1.y);
            l2 = __hadd2(l2, *(const __half2*)&u2.x); h2 = __hadd2(h2, *(const __half2*)&u2.y);
            l3 = __hadd2(l3, *(const __half2*)&u3.x); h3 = __hadd2(h3, *(const __half2*)&u3.y);
        }
        for (; e < end; ++e) {
            int r = col[e];
            uint2 u = xs[(r << 4) + c];
            l0 = __hadd2(l0, *(const __half2*)&u.x);
            h0 = __hadd2(h0, *(const __half2*)&u.y);
        }
        // combine the 4 fp16 partial streams in fp32, mean, convert to fp16
        float2 fl0 = __half22float2(l0), fl1 = __half22float2(l1);
        float2 fl2 = __half22float2(l2), fl3 = __half22float2(l3);
        float2 fh0 = __half22float2(h0), fh1 = __half22float2(h1);
        float2 fh2 = __half22float2(h2), fh3 = __half22float2(h3);
        float inv = 1.0f / fmaxf((float)(end - beg), 1.0f);
        half4_t hm;
        hm[0] = (_Float16)(((fl0.x + fl1.x) + (fl2.x + fl3.x)) * inv);
        hm[1] = (_Float16)(((fl0.y + fl1.y) + (fl2.y + fl3.y)) * inv);
        hm[2] = (_Float16)(((fh0.x + fh1.x) + (fh2.x + fh3.x)) * inv);
        hm[3] = (_Float16)(((fh0.y + fh1.y) + (fh2.y + fh3.y)) * inv);
        *((half4_t*)&smh[local][c << 2]) = hm;
        *((uint2*)&sxh[local][c << 2]) = xdu;      // root already fp16
    }
    __syncthreads();   // block-wide: epilogue waves read all 16 nodes

    // ---- MFMA epilogue: this wave computes cols [wave*16, wave*16+16) ----
    int fcol = (wave << 4) + (lane & 15);
    int g4 = lane >> 4;
    const half4_t* BL = (const half4_t*)wl16;
    const half4_t* BR = (const half4_t*)wr16;
    floatx4 acc = {0.f, 0.f, 0.f, 0.f};
#pragma unroll
    for (int ks = 0; ks < 4; ++ks) {
        int ko = (ks << 4) + (g4 << 2);
        half4_t am = *((const half4_t*)&smh[lane & 15][ko]);
        half4_t ax = *((const half4_t*)&sxh[lane & 15][ko]);
        half4_t bw_l = BL[((ks << 2) + g4) * 64 + fcol];
        half4_t bw_r = BR[((ks << 2) + g4) * 64 + fcol];
        acc = __builtin_amdgcn_mfma_f32_16x16x16f16(am, bw_l, acc, 0, 0, 0);
        acc = __builtin_amdgcn_mfma_f32_16x16x16f16(ax, bw_r, acc, 0, 0, 0);
    }
    float bb = bl[fcol];
    int nb0 = bid * 16 + (g4 << 2);   // D row = node local = g4*4 + j
#pragma unroll
    for (int j = 0; j < 4; ++j) {
        int n2 = nb0 + j;
        if (n2 < n_dst) {
            float v = acc[j] + bb;
            if (RELU) v = fmaxf(v, 0.f);
            outh[(size_t)n2 * H + fcol] = __float2half(v);
        }
    }
}

// ---------- classifier: 4 edges per 16-lane group (8 row-loads in flight) ----------
// R12: doubled in-flight gathers (R11 had 2 edges/group; k_dot floor is
// 256MB/6.4TB/s ~ 40us, was latency-exposed). Per-edge fp32 math and op order
// unchanged -> bit-identical output.
__global__ __launch_bounds__(256) void k_dot(const __half* __restrict__ xu,
                                             const __half* __restrict__ xr,
                                             const int* __restrict__ eli,
                                             float* __restrict__ out, int L) {
    long long wv = (blockIdx.x * 256LL + threadIdx.x) >> 6;
    int lane = threadIdx.x & 63;
    int c = lane & 15, g = lane >> 4;
    long long e0 = wv * 16 + (long long)g * 4;
    if (e0 >= L) return;
    long long Lm1 = (long long)L - 1;
    long long e1 = (e0 + 1 < L) ? e0 + 1 : Lm1;
    long long e2 = (e0 + 2 < L) ? e0 + 2 : Lm1;
    long long e3 = (e0 + 3 < L) ? e0 + 3 : Lm1;
    int a0 = eli[e0], a1 = eli[e1], a2 = eli[e2], a3 = eli[e3];
    int b0 = eli[(long long)L + e0], b1 = eli[(long long)L + e1];
    int b2 = eli[(long long)L + e2], b3 = eli[(long long)L + e3];
    const uint2* XU = (const uint2*)xu;
    const uint2* XR = (const uint2*)xr;
    uint2 u0 = XU[(a0 << 4) + c], u1 = XU[(a1 << 4) + c];
    uint2 u2 = XU[(a2 << 4) + c], u3 = XU[(a3 << 4) + c];
    uint2 r0 = XR[(b0 << 4) + c], r1 = XR[(b1 << 4) + c];
    uint2 r2 = XR[(b2 << 4) + c], r3 = XR[(b3 << 4) + c];
    float p0, p1, p2, p3;
    {
        float2 ua = __half22float2(*(const __half2*)&u0.x), ub = __half22float2(*(const __half2*)&u0.y);
        float2 ra = __half22float2(*(const __half2*)&r0.x), rb = __half22float2(*(const __half2*)&r0.y);
        p0 = ua.x * ra.x; p0 = fmaf(ua.y, ra.y, p0); p0 = fmaf(ub.x, rb.x, p0); p0 = fmaf(ub.y, rb.y, p0);
    }
    {
        float2 ua = __half22float2(*(const __half2*)&u1.x), ub = __half22float2(*(const __half2*)&u1.y);
        float2 ra = __half22float2(*(const __half2*)&r1.x), rb = __half22float2(*(const __half2*)&r1.y);
        p1 = ua.x * ra.x; p1 = fmaf(ua.y, ra.y, p1); p1 = fmaf(ub.x, rb.x, p1); p1 = fmaf(ub.y, rb.y, p1);
    }
    {
        float2 ua = __half22float2(*(const __half2*)&u2.x), ub = __half22float2(*(const __half2*)&u2.y);
        float2 ra = __half22float2(*(const __half2*)&r2.x), rb = __half22float2(*(const __half2*)&r2.y);
        p2 = ua.x * ra.x; p2 = fmaf(ua.y, ra.y, p2); p2 = fmaf(ub.x, rb.x, p2); p2 = fmaf(ub.y, rb.y, p2);
    }
    {
        float2 ua = __half22float2(*(const __half2*)&u3.x), ub = __half22float2(*(const __half2*)&u3.y);
        float2 ra = __half22float2(*(const __half2*)&r3.x), rb = __half22float2(*(const __half2*)&r3.y);
        p3 = ua.x * ra.x; p3 = fmaf(ua.y, ra.y, p3); p3 = fmaf(ub.x, rb.x, p3); p3 = fmaf(ub.y, rb.y, p3);
    }
#pragma unroll
    for (int off = 1; off < 16; off <<= 1) {
        p0 += __shfl_xor(p0, off);
        p1 += __shfl_xor(p1, off);
        p2 += __shfl_xor(p2, off);
        p3 += __shfl_xor(p3, off);
    }
    if (c == 0) {
        out[e0] = p0;
        if (e0 + 1 < L) out[e0 + 1] = p1;
        if (e0 + 2 < L) out[e0 + 2] = p2;
        if (e0 + 3 < L) out[e0 + 3] = p3;
    }
}

extern "C" void kernel_launch(void* const* d_in, const int* in_sizes, int n_in,
                              void* d_out, int out_size, void* d_ws, size_t ws_size,
                              hipStream_t stream) {
    const int*   uid        = (const int*)d_in[0];
    const int*   rid        = (const int*)d_in[1];
    const float* recipe_x   = (const float*)d_in[2];
    const int*   ei         = (const int*)d_in[3];
    const int*   eli        = (const int*)d_in[4];
    const float* user_emb   = (const float*)d_in[5];
    const float* recipe_emb = (const float*)d_in[6];
    const float* lin_w      = (const float*)d_in[7];
    const float* lin_b      = (const float*)d_in[8];
    const float* Wl         = (const float*)d_in[9];
    const float* bl         = (const float*)d_in[10];
    const float* Wr         = (const float*)d_in[11];

    const int Nu = in_sizes[0], Nr = in_sizes[1];
    const int E = in_sizes[3] / 2, L = in_sizes[4] / 2;
    const int nmax = (Nu > Nr) ? Nu : Nr;
    const int W = ((nmax - 1) >> WSH) + 1;   // 196 for N=200000

    char* ws = (char*)d_ws;
    size_t off = 0;
    auto alloc = [&](size_t bytes) -> char* {
        char* p = ws + off;
        off += (bytes + 255) & ~(size_t)255;
        return p;
    };
    // overlay region: slacked bin buffers (dead after k_build_win) share space
    // with the fp16 feature arrays [xh | yh]. Slack bufs = 2*256*BCAP*8 = 100MB
    // <= xh+yh = 102.4MB. Total ws footprint ~113MB.
    size_t hbytes = ((size_t)Nu + Nr) * H * 2;            // one fp16 feature set
    size_t bbytes = (size_t)2 * MAXW * BCAP * 8;          // slacked bufS,bufD
    size_t rbytes = 2 * hbytes;                           // xh + yh
    char* region  = alloc(rbytes > bbytes ? rbytes : bbytes);
    __half* xh_user   = (__half*)region;                  // init feats; layer-1 out
    __half* xh_recipe = (__half*)(region + (size_t)Nu * H * 2);
    __half* yh_user   = (__half*)(region + hbytes);       // layer-0 out
    __half* yh_recipe = (__half*)(region + hbytes + (size_t)Nu * H * 2);
    int2* bufS = (int2*)region;
    int2* bufD = (int2*)(region + (size_t)MAXW * BCAP * 8);
    int* rp_src  = (int*)alloc((size_t)(Nu + 1) * 4);
    int* rp_dst  = (int*)alloc((size_t)(Nr + 1) * 4);
    int* col_src = (int*)alloc((size_t)E * 4);
    int* col_dst = (int*)alloc((size_t)E * 4);
    int* baseS = (int*)alloc((MAXW + 1) * 4);
    int* baseD = (int*)alloc((MAXW + 1) * 4);
    int* curS  = (int*)alloc(MAXW * 4);
    int* curD  = (int*)alloc(MAXW * 4);
    _Float16* w16 = (_Float16*)alloc(8 * 4096 * 2);       // fp16 fragment-order weights
    (void)ws_size; (void)n_in; (void)out_size;

    // CSR build: cursor-init -> bin (single ei pass, slack buf) -> count scan
    // -> per-window hist+scan+scatter. No memsets, no count prepass.
    k_init_cur<<<1, 256, 0, stream>>>(curS, curD);
    k_bin<<<(E + BINCH - 1) / BINCH, 256, 0, stream>>>(ei, E, curS, curD, bufS, bufD);
    k_scan_win2<<<1, 256, 0, stream>>>(curS, curD, baseS, baseD);
    k_build_win<<<2 * W, 256, 0, stream>>>(bufS, bufD, curS, curD, baseS, baseD,
                                           rp_src, rp_dst, col_src, col_dst, Nu, Nr, W);

    // initial features (fp16 only) + fused weight prep (bufs dead by now)
    k_init_x<<<(nmax + 3) / 4, 256, 0, stream>>>(uid, rid, recipe_x, user_emb, recipe_emb,
                                                 lin_w, lin_b, Wl, Wr, w16,
                                                 xh_user, xh_recipe, Nu, Nr);

    int nbR = (Nr + 15) / 16, nbU = (Nu + 15) / 16;
    // w16 matrix m = layer*4 + rel*2 + lr, each 4096 elements
    // layer 0 (+ReLU): gather xh, root xh; out yh
    k_sage3<true><<<nbR + nbU, 256, 0, stream>>>(
        xh_user, xh_recipe, rp_dst, col_dst, w16 + 0 * 4096, w16 + 1 * 4096,
        bl + 0 * H, yh_recipe, Nr, nbR,
        xh_recipe, xh_user, rp_src, col_src, w16 + 2 * 4096, w16 + 3 * 4096,
        bl + 1 * H, yh_user, Nu);
    // layer 1 (no ReLU): gather yh, root yh; out xh (classifier input)
    k_sage3<false><<<nbR + nbU, 256, 0, stream>>>(
        yh_user, yh_recipe, rp_dst, col_dst, w16 + 4 * 4096, w16 + 5 * 4096,
        bl + 2 * H, xh_recipe, Nr, nbR,
        yh_recipe, yh_user, rp_src, col_src, w16 + 6 * 4096, w16 + 7 * 4096,
        bl + 3 * H, xh_user, Nu);

    // classifier: 64 edges per block
    long long nblk = ((long long)L + 63) / 64;
    k_dot<<<(int)nblk, 256, 0, stream>>>(xh_user, xh_recipe, eli, (float*)d_out, L);
}